// Round 10
// baseline (264.808 us; speedup 1.0000x reference)
//
#include <hip/hip_runtime.h>
#include <hip/hip_bf16.h>
#include <stdint.h>

#define TLEN 480
#define NB 128
#define NC 256

typedef short bf16x8 __attribute__((ext_vector_type(8)));
typedef float f32x4 __attribute__((ext_vector_type(4)));
typedef unsigned short u16;
typedef unsigned int u32;

__device__ inline u16 f2bf(float f) {   // RNE, used for the A operator (built once)
    union { float f; uint32_t u; } v; v.f = f;
    uint32_t u = v.u;
    return (u16)((u + 0x7fffu + ((u >> 16) & 1u)) >> 16);
}

// pack two fp32 -> (bf16(hi)<<16)|bf16(lo) by truncation: one v_perm_b32
__device__ inline u32 pack2bf(float lo, float hi) {
    return __builtin_amdgcn_perm(__float_as_uint(hi), __float_as_uint(lo), 0x07060302u);
}

// degree-1 LOESS weights; Q compile-time -> full unroll, w[] in registers.
// Arithmetic bit-identical to the original runtime-q version.
template<int N, int Q>
__device__ __forceinline__ int loess_wT(int t, float* out) {
    int left = t - (Q - 1) / 2;
    if (left < 0) left = 0;
    if (left > N - Q) left = N - Q;
    int right = left + Q - 1;
    int h = (t - left) > (right - t) ? (t - left) : (right - t);
    double w[Q];
    double wsum = 0.0;
    #pragma unroll
    for (int i = 0; i < Q; ++i) {
        double dist = fabs((double)(left + i - t)) / (double)h;
        double u = 1.0 - dist * dist * dist;
        if (u < 0.0) u = 0.0;
        double wv = u * u * u;
        w[i] = wv; wsum += wv;
    }
    #pragma unroll
    for (int i = 0; i < Q; ++i) w[i] /= wsum;
    double xbar = 0.0;
    #pragma unroll
    for (int i = 0; i < Q; ++i) xbar += w[i] * (double)(left + i);
    double var = 0.0;
    #pragma unroll
    for (int i = 0; i < Q; ++i) { double d = (double)(left + i) - xbar; var += w[i] * d * d; }
    if (var > 1e-12) {
        double tb = (double)t - xbar;
        #pragma unroll
        for (int i = 0; i < Q; ++i) {
            double d = (double)(left + i) - xbar;
            out[i] = (float)(w[i] * (1.0 + tb * d / var));
        }
    } else {
        #pragma unroll
        for (int i = 0; i < Q; ++i) out[i] = (float)w[i];
    }
    return left;
}

// Ms dense (34x32), MlpC (480x17 compact), MtC (480x29 compact), w3 (31-tap MA15*MA15*MA3)
__global__ void k_loess(float* Ms, float* w3, float* MlpC, float* MtC) {
    int gid = blockIdx.x * 256 + threadIdx.x;
    if (gid < 34) {
        float wl[7];
        int left = loess_wT<32, 7>(gid - 1, wl);
        float* row = Ms + gid * 32;
        #pragma unroll
        for (int i = 0; i < 32; ++i) row[i] = 0.0f;
        #pragma unroll
        for (int i = 0; i < 7; ++i) row[left + i] = wl[i];
    } else if (gid < 514) {
        int t = gid - 34;
        float wl[17];
        loess_wT<TLEN, 17>(t, wl);
        #pragma unroll
        for (int i = 0; i < 17; ++i) MlpC[t * 17 + i] = wl[i];
    } else if (gid < 994) {
        int t = gid - 514;
        float wl[29];
        loess_wT<TLEN, 29>(t, wl);
        #pragma unroll
        for (int i = 0; i < 29; ++i) MtC[t * 29 + i] = wl[i];
    } else if (gid < 1025) {
        int d = gid - 994;            // 0..30
        int cnt = 0;
        for (int c = 0; c < 3; ++c)
            for (int a = 0; a < 15; ++a) {
                int b = d - a - c;
                if (b >= 0 && b < 15) cnt++;
            }
        w3[d] = (float)((double)cnt / 675.0);
    }
}

// S[t][u] = Ecenter[t][u] - sum_{k<17} MlpC[t][k] * G[slp(t)+k][u]
__global__ void k_S(const float* __restrict__ Ms, const float* __restrict__ w3,
                    const float* __restrict__ MlpC, float* __restrict__ S) {
    int id = blockIdx.x * 256 + threadIdx.x;
    if (id >= TLEN * TLEN) return;
    int t = id / TLEN, u = id - t * TLEN;
    int nu = u / 15, ju = u - nu * 15;
    int slp = t - 8;
    if (slp < 0) slp = 0;
    if (slp > TLEN - 17) slp = TLEN - 17;
    float acc = 0.0f;
    for (int k = 0; k < 17; ++k) {
        int i = slp + k;
        int s_lo = (i - ju + 14) / 15;
        float g = 0.0f;
        #pragma unroll
        for (int ds = 0; ds < 3; ++ds) {
            int s = s_lo + ds;
            int d = s * 15 + ju - i;
            if (s >= 0 && s < 34 && d >= 0 && d <= 30)
                g += Ms[s * 32 + nu] * w3[d];
        }
        acc += MlpC[t * 17 + k] * g;
    }
    float val = -acc;
    if (t % 15 == ju) val += Ms[(1 + t / 15) * 32 + nu];
    S[id] = val;
}

// V = Mt @ S (banded 29), U = Mt - V (Mt from compact).  S rows are coalesced
// reads and S (0.92 MB) is L2-resident after k_S.
__global__ void k_VU(const float* __restrict__ MtC, const float* __restrict__ S,
                     float* __restrict__ U, float* __restrict__ V) {
    int id = blockIdx.x * 256 + threadIdx.x;
    if (id >= TLEN * TLEN) return;
    int t = id / TLEN, u = id - t * TLEN;
    int st = t - 14;
    if (st < 0) st = 0;
    if (st > TLEN - 29) st = TLEN - 29;
    float acc = 0.0f;
    for (int k = 0; k < 29; ++k)
        acc += MtC[t * 29 + k] * S[(size_t)(st + k) * TLEN + u];
    float mt = (u >= st && u < st + 29) ? MtC[t * 29 + (u - st)] : 0.0f;
    V[id] = acc;
    U[id] = mt - acc;
}

// A = U + V@U, bf16 out.  48x48 tile per block (100 blocks), 3x3 register
// blocking per thread, K-chunks of 32 (30 barriers vs old 60; 9 outputs/thread
// vs 1).  Per-output accumulation is k-ASCENDING exactly like the old kernel
// (old: kt-chunks of 16, e ascending => k = 0..479 in order; new: k0-chunks of
// 32, kk ascending => same order) -> bit-identical A, no absmax risk.
// Staging coalesced; inner-loop LDS reads bank-conflict-free (V rows stride 33:
// 16 lanes hit 16 distinct banks; U reads consecutive).
__global__ __launch_bounds__(256)
void k_A(const float* __restrict__ U, const float* __restrict__ V,
         u16* __restrict__ Abf) {
    __shared__ float Vt[48 * 33];    // 6,336 B
    __shared__ float Ut[32 * 49];    // 6,272 B
    int tid = threadIdx.x;
    int tx = tid & 15, ty = tid >> 4;
    int u0 = blockIdx.x * 48, t0 = blockIdx.y * 48;

    float acc[3][3] = {};
    for (int k0 = 0; k0 < TLEN; k0 += 32) {
        // stage V[t0:t0+48, k0:k0+32] and U[k0:k0+32, u0:u0+48]
        #pragma unroll
        for (int v = 0; v < 6; ++v) {
            int idx = v * 256 + tid;               // 0..1535
            int r = idx >> 5, c = idx & 31;
            Vt[r * 33 + c] = V[(size_t)(t0 + r) * TLEN + k0 + c];
        }
        #pragma unroll
        for (int v = 0; v < 6; ++v) {
            int idx = v * 256 + tid;               // 0..1535
            int r = idx / 48, c = idx - r * 48;
            Ut[r * 49 + c] = U[(size_t)(k0 + r) * TLEN + u0 + c];
        }
        __syncthreads();
        for (int kk = 0; kk < 32; ++kk) {          // k ascending: bit-identical order
            float vv[3], uu[3];
            #pragma unroll
            for (int i = 0; i < 3; ++i) vv[i] = Vt[(ty + 16 * i) * 33 + kk];
            #pragma unroll
            for (int j = 0; j < 3; ++j) uu[j] = Ut[kk * 49 + tx + 16 * j];
            #pragma unroll
            for (int i = 0; i < 3; ++i)
                #pragma unroll
                for (int j = 0; j < 3; ++j)
                    acc[i][j] += vv[i] * uu[j];
        }
        __syncthreads();
    }
    #pragma unroll
    for (int i = 0; i < 3; ++i) {
        int t = t0 + ty + 16 * i;
        #pragma unroll
        for (int j = 0; j < 3; ++j) {
            int u = u0 + tx + 16 * j;
            float a = acc[i][j] + U[(size_t)t * TLEN + u];
            Abf[(size_t)t * TLEN + u] = f2bf(a);
        }
    }
}

// Fused transpose+GEMM: trend = A @ x_b^T per batch; out1 = trend, out0 = x - trend.
//
// v3 structure (empirical best: 80.3-81.5 us): grid (b, 5 t-tiles of 96, 4
// c-quarters of 64).  Full-K LDS staging (one burst, reg double-buffered), ONE
// barrier, barrier-free pipelined MFMA (6 MFMA/step/wave), LDS-transposed
// full-line epilogue (WRITE_SIZE pinned at the 126 MB compulsory minimum).
// This round: s_setprio(1) around the MFMA cluster (T5) -- co-resident blocks
// are in DIFFERENT phases here (one staging/VMEM while the other MFMAs), the
// role-diversity T5 needs; m190's null was a lockstep structure.
__global__ __launch_bounds__(256, 2)
void k_gemm(const u16* __restrict__ A, const float* __restrict__ x,
            float* __restrict__ out0, float* __restrict__ out1) {
    __shared__ u16 Xs[64 * 488];     // 62,464 B
    int b = blockIdx.x;
    int t0 = blockIdx.y * 96;
    int cz = blockIdx.z * 64;
    int tid = threadIdx.x;
    int wave = tid >> 6, lane = tid & 63;
    int lane15 = lane & 15, quad = lane >> 4;
    int wm = wave & 1, wn = wave >> 1;   // wave tile: 32c x 48t

    // ---- staging: x[b, 0:480, cz:cz+64] -> LDS bf16 [c][488] ----
    int wq  = tid & 15;      // c-quad (4 c's)
    int kkq = tid >> 4;      // k-quad (4 k's); pass covers 64 k
    const float* xp0 = x + (size_t)b * TLEN * NC + (size_t)(kkq * 4) * NC + cz + wq * 4;
    u32* l32 = (u32*)Xs;
    int lbase = (wq * 4) * 244 + kkq * 2;     // u32 offset; +244/channel, +32/pass

    float4 ra[4], rb[4];
    {
        #pragma unroll
        for (int q = 0; q < 4; ++q) ra[q] = *(const float4*)(xp0 + q * NC);
    }
    #pragma unroll
    for (int p = 0; p < 8; ++p) {
        float4* cur = (p & 1) ? rb : ra;
        float4* nxt = (p & 1) ? ra : rb;
        if (p < 7) {   // issue next pass's loads before consuming cur
            if (p + 1 < 7 || kkq < 8) {
                const float* xp = xp0 + (size_t)(p + 1) * 64 * NC;
                #pragma unroll
                for (int q = 0; q < 4; ++q) nxt[q] = *(const float4*)(xp + q * NC);
            }
        }
        if (p < 7 || kkq < 8) {
            const float* fl = (const float*)cur;   // [r*4 + cc], compile-time indexed
            int o = lbase + p * 32;
            #pragma unroll
            for (int cc = 0; cc < 4; ++cc) {
                uint2 w;
                w.x = pack2bf(fl[0 * 4 + cc], fl[1 * 4 + cc]);
                w.y = pack2bf(fl[2 * 4 + cc], fl[3 * 4 + cc]);
                *(uint2*)(l32 + o + cc * 244) = w;
            }
        }
    }
    __syncthreads();   // barrier #1: LDS x-tile complete

    // ---- compute: 15 k-steps, software-pipelined, no barriers ----
    const u16* bp0 = A + (size_t)(t0 + wn * 48 + lane15) * TLEN + quad * 8;
    int arow = (wm * 32 + lane15) * 488 + quad * 8;    // u16 index into Xs

    f32x4 acc[2][3] = {};
    bf16x8 bcur[3], bnxt[3], acur[2], anxt[2];
    #pragma unroll
    for (int j = 0; j < 3; ++j) bcur[j] = *(const bf16x8*)(bp0 + (size_t)j * 16 * TLEN);
    acur[0] = *(const bf16x8*)&Xs[arow];
    acur[1] = *(const bf16x8*)&Xs[arow + 16 * 488];

    #pragma unroll
    for (int s = 0; s < 15; ++s) {
        bf16x8* bc = (s & 1) ? bnxt : bcur;
        bf16x8* bn = (s & 1) ? bcur : bnxt;
        bf16x8* ac = (s & 1) ? anxt : acur;
        bf16x8* an = (s & 1) ? acur : anxt;
        if (s < 14) {
            int k = (s + 1) * 32;
            #pragma unroll
            for (int j = 0; j < 3; ++j)
                bn[j] = *(const bf16x8*)(bp0 + (size_t)j * 16 * TLEN + k);
            an[0] = *(const bf16x8*)&Xs[arow + k];
            an[1] = *(const bf16x8*)&Xs[arow + 16 * 488 + k];
        }
        __builtin_amdgcn_s_setprio(1);
        #pragma unroll
        for (int j = 0; j < 3; ++j) {
            acc[0][j] = __builtin_amdgcn_mfma_f32_16x16x32_bf16(ac[0], bc[j], acc[0][j], 0, 0, 0);
            acc[1][j] = __builtin_amdgcn_mfma_f32_16x16x32_bf16(ac[1], bc[j], acc[1][j], 0, 0, 0);
        }
        __builtin_amdgcn_s_setprio(0);
    }

    __syncthreads();   // barrier #2: everyone done reading Xs; safe to alias

    // ---- epilogue: acc -> LDS fp32 [96][68] (x2 tensors), then line-complete stores ----
    float* T = (float*)Xs;          // trend  [96][68] = 26,112 B
    float* R = T + 96 * 68;         // resid  [96][68]; total 52,224 <= 62,464
    #pragma unroll
    for (int j = 0; j < 3; ++j) {
        int tl = wn * 48 + j * 16 + lane15;
        #pragma unroll
        for (int i = 0; i < 2; ++i) {
            int clb = wm * 32 + i * 16 + quad * 4;
            f32x4 tv = acc[i][j];
            size_t gb = ((size_t)b * TLEN + t0 + tl) * NC + cz + clb;
            f32x4 xv = *(const f32x4*)(x + gb);
            *(f32x4*)&T[tl * 68 + clb] = tv;
            *(f32x4*)&R[tl * 68 + clb] = xv - tv;
        }
    }
    __syncthreads();   // barrier #3

    #pragma unroll
    for (int v = 0; v < 6; ++v) {
        int id = v * 256 + tid;
        int tl = id >> 4, c4 = (id & 15) * 4;
        size_t gb = ((size_t)b * TLEN + t0 + tl) * NC + cz + c4;
        f32x4 tv = *(const f32x4*)&T[tl * 68 + c4];
        f32x4 rv = *(const f32x4*)&R[tl * 68 + c4];
        __builtin_nontemporal_store(tv, (f32x4*)(out1 + gb));
        __builtin_nontemporal_store(rv, (f32x4*)(out0 + gb));
    }
}

extern "C" void kernel_launch(void* const* d_in, const int* in_sizes, int n_in,
                              void* d_out, int out_size, void* d_ws, size_t ws_size,
                              hipStream_t stream) {
    const float* x = (const float*)d_in[0];
    float* out0 = (float*)d_out;                           // seasonal + resid = x - trend
    float* out1 = (float*)d_out + (size_t)NB * TLEN * NC;  // trend

    char* ws = (char*)d_ws;
    size_t oMs  = 0;                       // 34*32*4 = 4352
    size_t oW3  = oMs + 4352;              // 128
    size_t oLpC = oW3 + 128;               // 480*17*4 = 32640
    size_t oMtC = oLpC + 32640;            // 480*29*4 = 55680
    size_t oS   = oMtC + 55680;            // 921600
    size_t oU   = oS + 921600;
    size_t oV   = oU + 921600;
    size_t oA   = oV + 921600;             // bf16 460800

    float* Ms   = (float*)(ws + oMs);
    float* w3   = (float*)(ws + oW3);
    float* MlpC = (float*)(ws + oLpC);
    float* MtC  = (float*)(ws + oMtC);
    float* S    = (float*)(ws + oS);
    float* U    = (float*)(ws + oU);
    float* V    = (float*)(ws + oV);
    u16*   Abf  = (u16*)(ws + oA);

    k_loess<<<5, 256, 0, stream>>>(Ms, w3, MlpC, MtC);
    k_S<<<900, 256, 0, stream>>>(Ms, w3, MlpC, S);
    k_VU<<<900, 256, 0, stream>>>(MtC, S, U, V);
    k_A<<<dim3(10, 10), 256, 0, stream>>>(U, V, Abf);
    k_gemm<<<dim3(NB, 5, 4), 256, 0, stream>>>(Abf, x, out0, out1);
}

// Round 11
// 264.022 us; speedup vs baseline: 1.0030x; 1.0030x over previous
//
#include <hip/hip_runtime.h>
#include <hip/hip_bf16.h>
#include <stdint.h>

#define TLEN 480
#define NB 128
#define NC 256

typedef short bf16x8 __attribute__((ext_vector_type(8)));
typedef float f32x4 __attribute__((ext_vector_type(4)));
typedef unsigned short u16;
typedef unsigned int u32;

__device__ inline u16 f2bf(float f) {   // RNE, used for the A operator (built once)
    union { float f; uint32_t u; } v; v.f = f;
    uint32_t u = v.u;
    return (u16)((u + 0x7fffu + ((u >> 16) & 1u)) >> 16);
}

// pack two fp32 -> (bf16(hi)<<16)|bf16(lo) by truncation: one v_perm_b32
__device__ inline u32 pack2bf(float lo, float hi) {
    return __builtin_amdgcn_perm(__float_as_uint(hi), __float_as_uint(lo), 0x07060302u);
}

// degree-1 LOESS weights; Q compile-time -> full unroll, w[] in registers.
// Arithmetic bit-identical to the original runtime-q version.
template<int N, int Q>
__device__ __forceinline__ int loess_wT(int t, float* out) {
    int left = t - (Q - 1) / 2;
    if (left < 0) left = 0;
    if (left > N - Q) left = N - Q;
    int right = left + Q - 1;
    int h = (t - left) > (right - t) ? (t - left) : (right - t);
    double w[Q];
    double wsum = 0.0;
    #pragma unroll
    for (int i = 0; i < Q; ++i) {
        double dist = fabs((double)(left + i - t)) / (double)h;
        double u = 1.0 - dist * dist * dist;
        if (u < 0.0) u = 0.0;
        double wv = u * u * u;
        w[i] = wv; wsum += wv;
    }
    #pragma unroll
    for (int i = 0; i < Q; ++i) w[i] /= wsum;
    double xbar = 0.0;
    #pragma unroll
    for (int i = 0; i < Q; ++i) xbar += w[i] * (double)(left + i);
    double var = 0.0;
    #pragma unroll
    for (int i = 0; i < Q; ++i) { double d = (double)(left + i) - xbar; var += w[i] * d * d; }
    if (var > 1e-12) {
        double tb = (double)t - xbar;
        #pragma unroll
        for (int i = 0; i < Q; ++i) {
            double d = (double)(left + i) - xbar;
            out[i] = (float)(w[i] * (1.0 + tb * d / var));
        }
    } else {
        #pragma unroll
        for (int i = 0; i < Q; ++i) out[i] = (float)w[i];
    }
    return left;
}

// Ms dense (34x32), MlpC (480x17 compact), MtC (480x29 compact), w3 (31-tap MA15*MA15*MA3)
__global__ void k_loess(float* Ms, float* w3, float* MlpC, float* MtC) {
    int gid = blockIdx.x * 256 + threadIdx.x;
    if (gid < 34) {
        float wl[7];
        int left = loess_wT<32, 7>(gid - 1, wl);
        float* row = Ms + gid * 32;
        #pragma unroll
        for (int i = 0; i < 32; ++i) row[i] = 0.0f;
        #pragma unroll
        for (int i = 0; i < 7; ++i) row[left + i] = wl[i];
    } else if (gid < 514) {
        int t = gid - 34;
        float wl[17];
        loess_wT<TLEN, 17>(t, wl);
        #pragma unroll
        for (int i = 0; i < 17; ++i) MlpC[t * 17 + i] = wl[i];
    } else if (gid < 994) {
        int t = gid - 514;
        float wl[29];
        loess_wT<TLEN, 29>(t, wl);
        #pragma unroll
        for (int i = 0; i < 29; ++i) MtC[t * 29 + i] = wl[i];
    } else if (gid < 1025) {
        int d = gid - 994;            // 0..30
        int cnt = 0;
        for (int c = 0; c < 3; ++c)
            for (int a = 0; a < 15; ++a) {
                int b = d - a - c;
                if (b >= 0 && b < 15) cnt++;
            }
        w3[d] = (float)((double)cnt / 675.0);
    }
}

// S[t][u] = Ecenter[t][u] - sum_{k<17} MlpC[t][k] * G[slp(t)+k][u]
__global__ void k_S(const float* __restrict__ Ms, const float* __restrict__ w3,
                    const float* __restrict__ MlpC, float* __restrict__ S) {
    int id = blockIdx.x * 256 + threadIdx.x;
    if (id >= TLEN * TLEN) return;
    int t = id / TLEN, u = id - t * TLEN;
    int nu = u / 15, ju = u - nu * 15;
    int slp = t - 8;
    if (slp < 0) slp = 0;
    if (slp > TLEN - 17) slp = TLEN - 17;
    float acc = 0.0f;
    for (int k = 0; k < 17; ++k) {
        int i = slp + k;
        int s_lo = (i - ju + 14) / 15;
        float g = 0.0f;
        #pragma unroll
        for (int ds = 0; ds < 3; ++ds) {
            int s = s_lo + ds;
            int d = s * 15 + ju - i;
            if (s >= 0 && s < 34 && d >= 0 && d <= 30)
                g += Ms[s * 32 + nu] * w3[d];
        }
        acc += MlpC[t * 17 + k] * g;
    }
    float val = -acc;
    if (t % 15 == ju) val += Ms[(1 + t / 15) * 32 + nu];
    S[id] = val;
}

// V = Mt @ S (banded 29), U = Mt - V (Mt from compact).  S rows are coalesced
// reads and S (0.92 MB) is L2-resident after k_S.
__global__ void k_VU(const float* __restrict__ MtC, const float* __restrict__ S,
                     float* __restrict__ U, float* __restrict__ V) {
    int id = blockIdx.x * 256 + threadIdx.x;
    if (id >= TLEN * TLEN) return;
    int t = id / TLEN, u = id - t * TLEN;
    int st = t - 14;
    if (st < 0) st = 0;
    if (st > TLEN - 29) st = TLEN - 29;
    float acc = 0.0f;
    for (int k = 0; k < 29; ++k)
        acc += MtC[t * 29 + k] * S[(size_t)(st + k) * TLEN + u];
    float mt = (u >= st && u < st + 29) ? MtC[t * 29 + (u - st)] : 0.0f;
    V[id] = acc;
    U[id] = mt - acc;
}

// A = U + V@U, bf16 out.  48x48 tile per block (100 blocks), 3x3 register
// blocking, K-chunks of 32.  Per-output accumulation is k-ascending exactly
// like the original kernel -> bit-identical A.
__global__ __launch_bounds__(256)
void k_A(const float* __restrict__ U, const float* __restrict__ V,
         u16* __restrict__ Abf) {
    __shared__ float Vt[48 * 33];    // 6,336 B
    __shared__ float Ut[32 * 49];    // 6,272 B
    int tid = threadIdx.x;
    int tx = tid & 15, ty = tid >> 4;
    int u0 = blockIdx.x * 48, t0 = blockIdx.y * 48;

    float acc[3][3] = {};
    for (int k0 = 0; k0 < TLEN; k0 += 32) {
        #pragma unroll
        for (int v = 0; v < 6; ++v) {
            int idx = v * 256 + tid;               // 0..1535
            int r = idx >> 5, c = idx & 31;
            Vt[r * 33 + c] = V[(size_t)(t0 + r) * TLEN + k0 + c];
        }
        #pragma unroll
        for (int v = 0; v < 6; ++v) {
            int idx = v * 256 + tid;               // 0..1535
            int r = idx / 48, c = idx - r * 48;
            Ut[r * 49 + c] = U[(size_t)(k0 + r) * TLEN + u0 + c];
        }
        __syncthreads();
        for (int kk = 0; kk < 32; ++kk) {          // k ascending: bit-identical order
            float vv[3], uu[3];
            #pragma unroll
            for (int i = 0; i < 3; ++i) vv[i] = Vt[(ty + 16 * i) * 33 + kk];
            #pragma unroll
            for (int j = 0; j < 3; ++j) uu[j] = Ut[kk * 49 + tx + 16 * j];
            #pragma unroll
            for (int i = 0; i < 3; ++i)
                #pragma unroll
                for (int j = 0; j < 3; ++j)
                    acc[i][j] += vv[i] * uu[j];
        }
        __syncthreads();
    }
    #pragma unroll
    for (int i = 0; i < 3; ++i) {
        int t = t0 + ty + 16 * i;
        #pragma unroll
        for (int j = 0; j < 3; ++j) {
            int u = u0 + tx + 16 * j;
            float a = acc[i][j] + U[(size_t)t * TLEN + u];
            Abf[(size_t)t * TLEN + u] = f2bf(a);
        }
    }
}

// Fused transpose+GEMM: trend = A @ x_b^T per batch; out1 = trend, out0 = x - trend.
//
// v3 structure + chunk-XOR LDS swizzle (T2): the 16B chunk index within each
// LDS row is XORed with ((c>>2)&3).  Staging writes previously hit only 8
// bank-pairs x 8 lanes (2-way, 10.3M conflict cycles = ~17 us/CU of LDS-pipe
// serialization); with the swizzle, wq spreads to {0,8,16,24} -> 16 banks x 4
// lanes = the wave64 b64 structural minimum.  The A-frag read keeps its uniform
// 8/bank profile (XOR permutes quad within each 4-row group; start multiset
// unchanged).  Same arithmetic, bit-identical output.
__global__ __launch_bounds__(256, 2)
void k_gemm(const u16* __restrict__ A, const float* __restrict__ x,
            float* __restrict__ out0, float* __restrict__ out1) {
    __shared__ u16 Xs[64 * 488];     // 62,464 B
    int b = blockIdx.x;
    int t0 = blockIdx.y * 96;
    int cz = blockIdx.z * 64;
    int tid = threadIdx.x;
    int wave = tid >> 6, lane = tid & 63;
    int lane15 = lane & 15, quad = lane >> 4;
    int wm = wave & 1, wn = wave >> 1;   // wave tile: 32c x 48t

    // ---- staging: x[b, 0:480, cz:cz+64] -> LDS bf16 [c][488], chunk-swizzled ----
    int wq  = tid & 15;      // c-quad (4 c's)
    int kkq = tid >> 4;      // k-quad (4 k's); pass covers 64 k
    int sw  = wq & 3;        // chunk XOR swizzle for all 4 channels of this thread
    const float* xp0 = x + (size_t)b * TLEN * NC + (size_t)(kkq * 4) * NC + cz + wq * 4;
    u32* l32 = (u32*)Xs;
    int klo = (kkq & 1) * 2;            // u32 sub-offset within 16B chunk
    int kch = kkq >> 1;                 // chunk contribution from kkq

    float4 ra[4], rb[4];
    {
        #pragma unroll
        for (int q = 0; q < 4; ++q) ra[q] = *(const float4*)(xp0 + q * NC);
    }
    #pragma unroll
    for (int p = 0; p < 8; ++p) {
        float4* cur = (p & 1) ? rb : ra;
        float4* nxt = (p & 1) ? ra : rb;
        if (p < 7) {   // issue next pass's loads before consuming cur
            if (p + 1 < 7 || kkq < 8) {
                const float* xp = xp0 + (size_t)(p + 1) * 64 * NC;
                #pragma unroll
                for (int q = 0; q < 4; ++q) nxt[q] = *(const float4*)(xp + q * NC);
            }
        }
        if (p < 7 || kkq < 8) {
            const float* fl = (const float*)cur;   // [q*4 + cc], compile-time indexed
            int koff = ((p * 8 + kch) ^ sw) * 4 + klo;   // swizzled u32 offset in row
            int o = (wq * 4) * 244 + koff;
            #pragma unroll
            for (int cc = 0; cc < 4; ++cc) {
                uint2 w;
                w.x = pack2bf(fl[0 * 4 + cc], fl[1 * 4 + cc]);
                w.y = pack2bf(fl[2 * 4 + cc], fl[3 * 4 + cc]);
                *(uint2*)(l32 + o + cc * 244) = w;
            }
        }
    }
    __syncthreads();   // barrier #1: LDS x-tile complete

    // ---- compute: 15 k-steps, software-pipelined, no barriers ----
    const u16* bp0 = A + (size_t)(t0 + wn * 48 + lane15) * TLEN + quad * 8;
    int qp = quad ^ (lane15 >> 2);                     // read-side swizzle
    int arow = (wm * 32 + lane15) * 488 + qp * 8;      // u16 index into Xs

    f32x4 acc[2][3] = {};
    bf16x8 bcur[3], bnxt[3], acur[2], anxt[2];
    #pragma unroll
    for (int j = 0; j < 3; ++j) bcur[j] = *(const bf16x8*)(bp0 + (size_t)j * 16 * TLEN);
    acur[0] = *(const bf16x8*)&Xs[arow];
    acur[1] = *(const bf16x8*)&Xs[arow + 16 * 488];

    #pragma unroll
    for (int s = 0; s < 15; ++s) {
        bf16x8* bc = (s & 1) ? bnxt : bcur;
        bf16x8* bn = (s & 1) ? bcur : bnxt;
        bf16x8* ac = (s & 1) ? anxt : acur;
        bf16x8* an = (s & 1) ? acur : anxt;
        if (s < 14) {
            int k = (s + 1) * 32;
            #pragma unroll
            for (int j = 0; j < 3; ++j)
                bn[j] = *(const bf16x8*)(bp0 + (size_t)j * 16 * TLEN + k);
            an[0] = *(const bf16x8*)&Xs[arow + k];
            an[1] = *(const bf16x8*)&Xs[arow + 16 * 488 + k];
        }
        __builtin_amdgcn_s_setprio(1);
        #pragma unroll
        for (int j = 0; j < 3; ++j) {
            acc[0][j] = __builtin_amdgcn_mfma_f32_16x16x32_bf16(ac[0], bc[j], acc[0][j], 0, 0, 0);
            acc[1][j] = __builtin_amdgcn_mfma_f32_16x16x32_bf16(ac[1], bc[j], acc[1][j], 0, 0, 0);
        }
        __builtin_amdgcn_s_setprio(0);
    }

    __syncthreads();   // barrier #2: everyone done reading Xs; safe to alias

    // ---- epilogue: acc -> LDS fp32 [96][68] (x2 tensors), then line-complete stores ----
    float* T = (float*)Xs;          // trend  [96][68] = 26,112 B
    float* R = T + 96 * 68;         // resid  [96][68]; total 52,224 <= 62,464
    #pragma unroll
    for (int j = 0; j < 3; ++j) {
        int tl = wn * 48 + j * 16 + lane15;
        #pragma unroll
        for (int i = 0; i < 2; ++i) {
            int clb = wm * 32 + i * 16 + quad * 4;
            f32x4 tv = acc[i][j];
            size_t gb = ((size_t)b * TLEN + t0 + tl) * NC + cz + clb;
            f32x4 xv = *(const f32x4*)(x + gb);
            *(f32x4*)&T[tl * 68 + clb] = tv;
            *(f32x4*)&R[tl * 68 + clb] = xv - tv;
        }
    }
    __syncthreads();   // barrier #3

    #pragma unroll
    for (int v = 0; v < 6; ++v) {
        int id = v * 256 + tid;
        int tl = id >> 4, c4 = (id & 15) * 4;
        size_t gb = ((size_t)b * TLEN + t0 + tl) * NC + cz + c4;
        f32x4 tv = *(const f32x4*)&T[tl * 68 + c4];
        f32x4 rv = *(const f32x4*)&R[tl * 68 + c4];
        __builtin_nontemporal_store(tv, (f32x4*)(out1 + gb));
        __builtin_nontemporal_store(rv, (f32x4*)(out0 + gb));
    }
}

extern "C" void kernel_launch(void* const* d_in, const int* in_sizes, int n_in,
                              void* d_out, int out_size, void* d_ws, size_t ws_size,
                              hipStream_t stream) {
    const float* x = (const float*)d_in[0];
    float* out0 = (float*)d_out;                           // seasonal + resid = x - trend
    float* out1 = (float*)d_out + (size_t)NB * TLEN * NC;  // trend

    char* ws = (char*)d_ws;
    size_t oMs  = 0;                       // 34*32*4 = 4352
    size_t oW3  = oMs + 4352;              // 128
    size_t oLpC = oW3 + 128;               // 480*17*4 = 32640
    size_t oMtC = oLpC + 32640;            // 480*29*4 = 55680
    size_t oS   = oMtC + 55680;            // 921600
    size_t oU   = oS + 921600;
    size_t oV   = oU + 921600;
    size_t oA   = oV + 921600;             // bf16 460800

    float* Ms   = (float*)(ws + oMs);
    float* w3   = (float*)(ws + oW3);
    float* MlpC = (float*)(ws + oLpC);
    float* MtC  = (float*)(ws + oMtC);
    float* S    = (float*)(ws + oS);
    float* U    = (float*)(ws + oU);
    float* V    = (float*)(ws + oV);
    u16*   Abf  = (u16*)(ws + oA);

    k_loess<<<5, 256, 0, stream>>>(Ms, w3, MlpC, MtC);
    k_S<<<900, 256, 0, stream>>>(Ms, w3, MlpC, S);
    k_VU<<<900, 256, 0, stream>>>(MtC, S, U, V);
    k_A<<<dim3(10, 10), 256, 0, stream>>>(U, V, Abf);
    k_gemm<<<dim3(NB, 5, 4), 256, 0, stream>>>(Abf, x, out0, out1);
}